// Round 1
// baseline (3061.121 us; speedup 1.0000x reference)
//
#include <hip/hip_runtime.h>
#include <math.h>

#define BB 4
#define TT 2048
#define NEMB 256
#define NH 8
#define HD 32

// ---------------- Kernel A: qkv = x @ w_attn, packed per-head K/Q/V ----------
__global__ __launch_bounds__(256) void qkv_gemm(const float* __restrict__ x,
                                                const float* __restrict__ w,
                                                float* __restrict__ Kp,
                                                float* __restrict__ Qp,
                                                float* __restrict__ Vp) {
    const int c  = blockIdx.x * 256 + threadIdx.x;   // 0..767
    const int r0 = blockIdx.y * 8;                   // 8192 rows / 8
    float acc[8] = {0.f,0.f,0.f,0.f,0.f,0.f,0.f,0.f};
    const float* xrow = x + (long)r0 * NEMB;
    #pragma unroll 4
    for (int k = 0; k < NEMB; ++k) {
        const float wv = w[k * 768 + c];
        #pragma unroll
        for (int i = 0; i < 8; ++i)
            acc[i] += xrow[i * NEMB + k] * wv;
    }
    const int sec = c >> 8;          // 0=K, 1=Q, 2=V (jnp.split order!)
    const int cc  = c & 255;
    const int h   = cc >> 5;
    const int d   = cc & 31;
    float* dst = (sec == 0) ? Kp : (sec == 1) ? Qp : Vp;
    #pragma unroll
    for (int i = 0; i < 8; ++i) {
        const int r = r0 + i;
        const int b = r >> 11;       // / 2048
        const int t = r & 2047;
        dst[(((long)(b * NH + h) * TT) + t) * HD + d] = acc[i];
    }
}

// ---------------- Kernel B: online-softmax attention -------------------------
// One wave (64 lanes) per (b,h,t); 4 waves/block over consecutive t.
__global__ __launch_bounds__(256) void attn_kernel(const float* __restrict__ Kp,
                                                   const float* __restrict__ Qp,
                                                   const float* __restrict__ Vp,
                                                   const float* __restrict__ pe,
                                                   float* __restrict__ att) {
    const int lane = threadIdx.x & 63;
    const int wv   = threadIdx.x >> 6;
    const int t    = blockIdx.x * 4 + wv;
    const int h    = blockIdx.y;
    const int b    = blockIdx.z;
    const long bh  = b * NH + h;

    const float4* Q4 = (const float4*)(Qp + (bh * TT + t) * HD);
    float4 q[8];
    #pragma unroll
    for (int i = 0; i < 8; ++i) q[i] = Q4[i];

    float m = -1e30f, l = 0.f;
    float4 o[8];
    #pragma unroll
    for (int i = 0; i < 8; ++i) o[i] = make_float4(0.f,0.f,0.f,0.f);

    const float scale = 0.17677669529663687f;   // 1/sqrt(32)
    const float4* Kbase = (const float4*)(Kp + bh * TT * HD);
    const float4* Vbase = (const float4*)(Vp + bh * TT * HD);
    const float4* Pbase = (const float4*)(pe + (long)h * TT * HD);

    for (int s = lane; s <= t; s += 64) {
        const float4* Kr = Kbase + s * 8;
        const float4* Pr = Pbase + (TT - 1 - t + s) * 8;
        float sc = 0.f;
        #pragma unroll
        for (int i = 0; i < 8; ++i) {
            const float4 kv = Kr[i];
            const float4 pv = Pr[i];
            sc += q[i].x * (kv.x + pv.x) + q[i].y * (kv.y + pv.y)
                + q[i].z * (kv.z + pv.z) + q[i].w * (kv.w + pv.w);
        }
        sc *= scale;
        const float nm   = fmaxf(m, sc);
        const float p    = __expf(sc - nm);
        const float corr = __expf(m - nm);   // first iter: exp(-1e30)->0
        const float4* Vr = Vbase + s * 8;
        l = l * corr + p;
        #pragma unroll
        for (int i = 0; i < 8; ++i) {
            const float4 vvv = Vr[i];
            o[i].x = o[i].x * corr + p * vvv.x;
            o[i].y = o[i].y * corr + p * vvv.y;
            o[i].z = o[i].z * corr + p * vvv.z;
            o[i].w = o[i].w * corr + p * vvv.w;
        }
        m = nm;
    }

    // ---- wave reduction (width 64) ----
    const float mloc = m;
    #pragma unroll
    for (int off = 32; off >= 1; off >>= 1) m = fmaxf(m, __shfl_xor(m, off));
    const float lscale = __expf(mloc - m);   // 0 for lanes that did no work
    float lw = l * lscale;
    #pragma unroll
    for (int off = 32; off >= 1; off >>= 1) lw += __shfl_xor(lw, off);

    __shared__ float red[4][64][33];
    #pragma unroll
    for (int i = 0; i < 8; ++i) {
        red[wv][lane][4*i+0] = o[i].x * lscale;
        red[wv][lane][4*i+1] = o[i].y * lscale;
        red[wv][lane][4*i+2] = o[i].z * lscale;
        red[wv][lane][4*i+3] = o[i].w * lscale;
    }
    __syncthreads();
    if (lane < 32) {
        float v = 0.f;
        #pragma unroll 8
        for (int i = 0; i < 64; ++i) v += red[wv][i][lane];
        att[((long)(b * TT + t) * NEMB) + h * HD + lane] = v / lw;
    }
}

// ---------------- Kernel C: out = att @ w_proj + b_proj ----------------------
__global__ __launch_bounds__(256) void proj_gemm(const float* __restrict__ att,
                                                 const float* __restrict__ w,
                                                 const float* __restrict__ bias,
                                                 float* __restrict__ out) {
    const int c  = threadIdx.x;          // 0..255
    const int r0 = blockIdx.x * 8;
    float acc[8] = {0.f,0.f,0.f,0.f,0.f,0.f,0.f,0.f};
    const float* arow = att + (long)r0 * NEMB;
    #pragma unroll 4
    for (int k = 0; k < NEMB; ++k) {
        const float wvv = w[k * NEMB + c];
        #pragma unroll
        for (int i = 0; i < 8; ++i)
            acc[i] += arow[i * NEMB + k] * wvv;
    }
    const float bv = bias[c];
    #pragma unroll
    for (int i = 0; i < 8; ++i)
        out[(long)(r0 + i) * NEMB + c] = acc[i] + bv;
}

extern "C" void kernel_launch(void* const* d_in, const int* in_sizes, int n_in,
                              void* d_out, int out_size, void* d_ws, size_t ws_size,
                              hipStream_t stream) {
    const float* x      = (const float*)d_in[0];
    const float* w_attn = (const float*)d_in[1];
    const float* pe     = (const float*)d_in[2];
    const float* w_proj = (const float*)d_in[3];
    const float* b_proj = (const float*)d_in[4];
    float* out = (float*)d_out;

    float* ws  = (float*)d_ws;
    const long SZ = (long)BB * NH * TT * HD;  // 2,097,152 elements = 8 MB
    float* Kp  = ws;
    float* Qp  = ws + SZ;
    float* Vp  = ws + 2 * SZ;
    float* att = ws + 3 * SZ;

    qkv_gemm<<<dim3(3, 1024), 256, 0, stream>>>(x, w_attn, Kp, Qp, Vp);
    attn_kernel<<<dim3(TT / 4, NH, BB), 256, 0, stream>>>(Kp, Qp, Vp, pe, att);
    proj_gemm<<<dim3(1024), 256, 0, stream>>>(att, w_proj, b_proj, out);
}

// Round 2
// 494.464 us; speedup vs baseline: 6.1908x; 6.1908x over previous
//
#include <hip/hip_runtime.h>
#include <math.h>

#define BB 4
#define TT 2048
#define NEMB 256
#define NH 8
#define HD 32

// ---------------- Kernel A: qkv = x @ w_attn, packed per-head K/Q/V ----------
__global__ __launch_bounds__(256) void qkv_gemm(const float* __restrict__ x,
                                                const float* __restrict__ w,
                                                float* __restrict__ Kp,
                                                float* __restrict__ Qp,
                                                float* __restrict__ Vp) {
    const int c  = blockIdx.x * 256 + threadIdx.x;   // 0..767
    const int r0 = blockIdx.y * 8;                   // 8192 rows / 8
    float acc[8] = {0.f,0.f,0.f,0.f,0.f,0.f,0.f,0.f};
    const float* xrow = x + (long)r0 * NEMB;
    #pragma unroll 4
    for (int k = 0; k < NEMB; ++k) {
        const float wv = w[k * 768 + c];
        #pragma unroll
        for (int i = 0; i < 8; ++i)
            acc[i] += xrow[i * NEMB + k] * wv;
    }
    const int sec = c >> 8;          // 0=K, 1=Q, 2=V (jnp.split order!)
    const int cc  = c & 255;
    const int h   = cc >> 5;
    const int d   = cc & 31;
    float* dst = (sec == 0) ? Kp : (sec == 1) ? Qp : Vp;
    #pragma unroll
    for (int i = 0; i < 8; ++i) {
        const int r = r0 + i;
        const int b = r >> 11;       // / 2048
        const int t = r & 2047;
        dst[(((long)(b * NH + h) * TT) + t) * HD + d] = acc[i];
    }
}

// ---------------- Kernel B: tiled two-phase flash attention ------------------
// Block: 256 threads, one (b,h), processes t-tiles {bx, 31-bx} (uniform work).
// Score phase: thread (ty,tx) computes 4t x 4s scores from transposed LDS tiles.
// PV phase: P via LDS round-trip (overlaid on K/pe region), thread = 2t x 4d.
__global__ __launch_bounds__(256) void attn_kernel(const float* __restrict__ Kp,
                                                   const float* __restrict__ Qp,
                                                   const float* __restrict__ Vp,
                                                   const float* __restrict__ pe,
                                                   float* __restrict__ att) {
    __shared__ float lds[11072];                 // 44288 B
    float* QsT   = lds;                          // [32][68] transposed Q
    float* Vs    = lds + 2176;                   // [64][36]
    float* Ms    = lds + 4480;                   // [64] row max
    float* Ls    = Ms + 64;                      // [64] row sum
    float* CorrS = Ls + 64;                      // [64] per-tile rescale
    float* Rgn   = lds + 4672;                   // overlay region (6400 floats)
    float* KsT   = Rgn;                          // [32][68] transposed K
    float* PEsT  = Rgn + 2176;                   // [32][132] transposed pe window
    float* Ps    = Rgn;                          // [64][68] P tile (overlay)

    const int tid = threadIdx.x;
    const int tx = tid & 15, ty = tid >> 4;
    const int b = blockIdx.z, h = blockIdx.y;
    const long bh = (long)b * NH + h;
    const float* Kg = Kp + bh * TT * HD;
    const float* Qg = Qp + bh * TT * HD;
    const float* Vg = Vp + bh * TT * HD;
    const float* Pg = pe + (long)h * TT * HD;
    const float scale = 0.17677669529663687f;    // 1/sqrt(32)

    const int pr  = tid >> 3;                    // PV: rows 2pr, 2pr+1
    const int pdc = (tid & 7) * 4;               // PV: d chunk

    for (int half = 0; half < 2; ++half) {
        const int itile = half ? (31 - (int)blockIdx.x) : (int)blockIdx.x;
        const int t0 = itile * 64;

        __syncthreads();                          // protect QsT/stats from prev half
        for (int i = tid; i < 512; i += 256) {    // stage Q transposed
            const int s = i >> 3, dg = (i & 7) * 4;
            const float4 v = *(const float4*)(Qg + (long)(t0 + s) * HD + dg);
            QsT[(dg+0)*68 + s] = v.x; QsT[(dg+1)*68 + s] = v.y;
            QsT[(dg+2)*68 + s] = v.z; QsT[(dg+3)*68 + s] = v.w;
        }
        if (tid < 64) { Ms[tid] = -1e30f; Ls[tid] = 0.0f; }
        float4 o0 = make_float4(0.f,0.f,0.f,0.f);
        float4 o1 = make_float4(0.f,0.f,0.f,0.f);

        const int nT = itile + 1;
        for (int jt = 0; jt < nT; ++jt) {
            const int s0 = jt * 64;
            __syncthreads();                      // prev PV done before region overwrite
            for (int i = tid; i < 512; i += 256) {   // stage K^T + V
                const int s = i >> 3, dg = (i & 7) * 4;
                const float4 kv = *(const float4*)(Kg + (long)(s0 + s) * HD + dg);
                KsT[(dg+0)*68 + s] = kv.x; KsT[(dg+1)*68 + s] = kv.y;
                KsT[(dg+2)*68 + s] = kv.z; KsT[(dg+3)*68 + s] = kv.w;
                const float4 vv = *(const float4*)(Vg + (long)(s0 + s) * HD + dg);
                *(float4*)(Vs + s * 36 + dg) = vv;
            }
            const int u0 = TT - 64 - t0 + s0;     // pe window base (>=0 always)
            for (int i = tid; i < 1024; i += 256) {  // stage pe^T, 128 rows
                const int ur = i >> 3, dg = (i & 7) * 4;
                const int u = u0 + ur;
                float4 pv = make_float4(0.f,0.f,0.f,0.f);
                if (u < TT) pv = *(const float4*)(Pg + (long)u * HD + dg);
                PEsT[(dg+0)*132 + ur] = pv.x; PEsT[(dg+1)*132 + ur] = pv.y;
                PEsT[(dg+2)*132 + ur] = pv.z; PEsT[(dg+3)*132 + ur] = pv.w;
            }
            __syncthreads();

            // ---- score phase: 4x4 per thread ----
            const int tb = ty * 4, sb = tx * 4;
            float sc[4][4];
            #pragma unroll
            for (int i = 0; i < 4; ++i)
                #pragma unroll
                for (int j = 0; j < 4; ++j) sc[i][j] = 0.f;
            // local pe row for (ti,si): 63 + (sb+si) - (tb+ti) -> base-3 aligned to 4
            const float* peBase = PEsT + (60 + sb - tb);
            #pragma unroll 4
            for (int d = 0; d < 32; ++d) {
                const float4 q4 = *(const float4*)(QsT + d*68 + tb);
                const float4 k4 = *(const float4*)(KsT + d*68 + sb);
                const float4 pA = *(const float4*)(peBase + d*132);
                const float4 pB = *(const float4*)(peBase + d*132 + 4);
                const float q[4]  = {q4.x,q4.y,q4.z,q4.w};
                const float k[4]  = {k4.x,k4.y,k4.z,k4.w};
                const float pe8[8]= {pA.x,pA.y,pA.z,pA.w,pB.x,pB.y,pB.z,pB.w};
                #pragma unroll
                for (int ti = 0; ti < 4; ++ti)
                    #pragma unroll
                    for (int si = 0; si < 4; ++si)
                        sc[ti][si] = fmaf(q[ti], k[si] + pe8[3 + si - ti], sc[ti][si]);
            }
            const bool diag = (jt == itile);
            #pragma unroll
            for (int ti = 0; ti < 4; ++ti)
                #pragma unroll
                for (int si = 0; si < 4; ++si) {
                    float v = sc[ti][si] * scale;
                    if (diag && (sb + si > tb + ti)) v = -1e30f;
                    sc[ti][si] = v;
                }

            // ---- online softmax (rows owned by one 16-lane group) ----
            float p[4][4], mnew[4], corr[4], rs[4];
            #pragma unroll
            for (int ti = 0; ti < 4; ++ti) {
                float mx = fmaxf(fmaxf(sc[ti][0], sc[ti][1]), fmaxf(sc[ti][2], sc[ti][3]));
                mx = fmaxf(mx, __shfl_xor(mx, 1));
                mx = fmaxf(mx, __shfl_xor(mx, 2));
                mx = fmaxf(mx, __shfl_xor(mx, 4));
                mx = fmaxf(mx, __shfl_xor(mx, 8));
                const float mold = Ms[tb + ti];
                const float mn = fmaxf(mold, mx);
                float s = 0.f;
                #pragma unroll
                for (int si = 0; si < 4; ++si) {
                    p[ti][si] = __expf(sc[ti][si] - mn);
                    s += p[ti][si];
                }
                s += __shfl_xor(s, 1); s += __shfl_xor(s, 2);
                s += __shfl_xor(s, 4); s += __shfl_xor(s, 8);
                mnew[ti] = mn; corr[ti] = __expf(mold - mn); rs[ti] = s;
            }
            if (tx == 0) {
                #pragma unroll
                for (int ti = 0; ti < 4; ++ti) {
                    const int r = tb + ti;
                    Ms[r] = mnew[ti]; CorrS[r] = corr[ti];
                    Ls[r] = Ls[r] * corr[ti] + rs[ti];
                }
            }
            __syncthreads();                      // all K/pe reads done before P overlay
            #pragma unroll
            for (int ti = 0; ti < 4; ++ti)
                *(float4*)(Ps + (tb + ti) * 68 + sb) =
                    make_float4(p[ti][0], p[ti][1], p[ti][2], p[ti][3]);
            __syncthreads();

            // ---- PV phase: thread = rows {2pr,2pr+1} x d-chunk pdc ----
            const float c0 = CorrS[2*pr], c1 = CorrS[2*pr + 1];
            o0.x *= c0; o0.y *= c0; o0.z *= c0; o0.w *= c0;
            o1.x *= c1; o1.y *= c1; o1.z *= c1; o1.w *= c1;
            const float* Pr0 = Ps + (2*pr) * 68;
            const float* Pr1 = Pr0 + 68;
            #pragma unroll 4
            for (int sg = 0; sg < 16; ++sg) {
                const float4 pa = *(const float4*)(Pr0 + sg*4);
                const float4 pb = *(const float4*)(Pr1 + sg*4);
                const float4 v0 = *(const float4*)(Vs + (sg*4+0)*36 + pdc);
                const float4 v1 = *(const float4*)(Vs + (sg*4+1)*36 + pdc);
                const float4 v2 = *(const float4*)(Vs + (sg*4+2)*36 + pdc);
                const float4 v3 = *(const float4*)(Vs + (sg*4+3)*36 + pdc);
                o0.x += pa.x*v0.x + pa.y*v1.x + pa.z*v2.x + pa.w*v3.x;
                o0.y += pa.x*v0.y + pa.y*v1.y + pa.z*v2.y + pa.w*v3.y;
                o0.z += pa.x*v0.z + pa.y*v1.z + pa.z*v2.z + pa.w*v3.z;
                o0.w += pa.x*v0.w + pa.y*v1.w + pa.z*v2.w + pa.w*v3.w;
                o1.x += pb.x*v0.x + pb.y*v1.x + pb.z*v2.x + pb.w*v3.x;
                o1.y += pb.x*v0.y + pb.y*v1.y + pb.z*v2.y + pb.w*v3.y;
                o1.z += pb.x*v0.z + pb.y*v1.z + pb.z*v2.z + pb.w*v3.z;
                o1.w += pb.x*v0.w + pb.y*v1.w + pb.z*v2.w + pb.w*v3.w;
            }
        }

        const float l0 = 1.0f / Ls[2*pr];
        const float l1 = 1.0f / Ls[2*pr + 1];
        const float4 r0 = make_float4(o0.x*l0, o0.y*l0, o0.z*l0, o0.w*l0);
        const float4 r1 = make_float4(o1.x*l1, o1.y*l1, o1.z*l1, o1.w*l1);
        *(float4*)(att + ((long)(b * TT + t0 + 2*pr)) * NEMB + h * HD + pdc) = r0;
        *(float4*)(att + ((long)(b * TT + t0 + 2*pr + 1)) * NEMB + h * HD + pdc) = r1;
    }
}

// ---------------- Kernel C: out = att @ w_proj + b_proj ----------------------
__global__ __launch_bounds__(256) void proj_gemm(const float* __restrict__ att,
                                                 const float* __restrict__ w,
                                                 const float* __restrict__ bias,
                                                 float* __restrict__ out) {
    const int c  = threadIdx.x;          // 0..255
    const int r0 = blockIdx.x * 8;
    float acc[8] = {0.f,0.f,0.f,0.f,0.f,0.f,0.f,0.f};
    const float* arow = att + (long)r0 * NEMB;
    #pragma unroll 4
    for (int k = 0; k < NEMB; ++k) {
        const float wvv = w[k * NEMB + c];
        #pragma unroll
        for (int i = 0; i < 8; ++i)
            acc[i] += arow[i * NEMB + k] * wvv;
    }
    const float bv = bias[c];
    #pragma unroll
    for (int i = 0; i < 8; ++i)
        out[(long)(r0 + i) * NEMB + c] = acc[i] + bv;
}

extern "C" void kernel_launch(void* const* d_in, const int* in_sizes, int n_in,
                              void* d_out, int out_size, void* d_ws, size_t ws_size,
                              hipStream_t stream) {
    const float* x      = (const float*)d_in[0];
    const float* w_attn = (const float*)d_in[1];
    const float* pe     = (const float*)d_in[2];
    const float* w_proj = (const float*)d_in[3];
    const float* b_proj = (const float*)d_in[4];
    float* out = (float*)d_out;

    float* ws  = (float*)d_ws;
    const long SZ = (long)BB * NH * TT * HD;  // 2,097,152 elements = 8 MB
    float* Kp  = ws;
    float* Qp  = ws + SZ;
    float* Vp  = ws + 2 * SZ;
    float* att = ws + 3 * SZ;

    qkv_gemm<<<dim3(3, 1024), 256, 0, stream>>>(x, w_attn, Kp, Qp, Vp);
    attn_kernel<<<dim3(16, NH, BB), 256, 0, stream>>>(Kp, Qp, Vp, pe, att);
    proj_gemm<<<dim3(1024), 256, 0, stream>>>(att, w_proj, b_proj, out);
}

// Round 3
// 262.005 us; speedup vs baseline: 11.6834x; 1.8872x over previous
//
#include <hip/hip_runtime.h>
#include <math.h>

#define BB 4
#define TT 2048
#define NEMB 256
#define NH 8
#define HD 32

typedef __attribute__((ext_vector_type(8))) short bf8;   // 8 x bf16 (4 VGPRs)
typedef __attribute__((ext_vector_type(4))) float f4;    // MFMA C/D

static __device__ __forceinline__ unsigned short f2bf(float f) {
    union { float f; unsigned u; } v; v.f = f;
    unsigned r = v.u + 0x7FFF + ((v.u >> 16) & 1);       // RNE
    return (unsigned short)(r >> 16);
}

// ---------------- Kernel A: qkv = x @ w_attn -> bf16 K, scaled Q, V^T --------
__global__ __launch_bounds__(256) void qkv_gemm(const float* __restrict__ x,
                                                const float* __restrict__ w,
                                                unsigned short* __restrict__ Kb,
                                                unsigned short* __restrict__ Qb,
                                                unsigned short* __restrict__ Vt) {
    const int c  = blockIdx.x * 256 + threadIdx.x;   // 0..767
    const int r0 = blockIdx.y * 8;                   // 8192 rows / 8
    float acc[8] = {0.f,0.f,0.f,0.f,0.f,0.f,0.f,0.f};
    const float* xrow = x + (long)r0 * NEMB;
    #pragma unroll 4
    for (int k = 0; k < NEMB; ++k) {
        const float wv = w[k * 768 + c];
        #pragma unroll
        for (int i = 0; i < 8; ++i)
            acc[i] += xrow[i * NEMB + k] * wv;
    }
    const int sec = c >> 8;          // 0=K, 1=Q, 2=V (jnp.split order!)
    const int cc  = c & 255;
    const int h   = cc >> 5;
    const int d   = cc & 31;
    #pragma unroll
    for (int i = 0; i < 8; ++i) {
        const int r = r0 + i;
        const int b = r >> 11;
        const int t = r & 2047;
        const long bh = b * NH + h;
        if (sec == 0)      Kb[(bh * TT + t) * HD + d] = f2bf(acc[i]);
        else if (sec == 1) Qb[(bh * TT + t) * HD + d] = f2bf(acc[i] * 0.17677669529663687f);
        else               Vt[(bh * HD + d) * TT + t] = f2bf(acc[i]);
    }
}

// ---------------- pe -> bf16 -------------------------------------------------
__global__ __launch_bounds__(256) void pe_cvt(const float* __restrict__ pe,
                                              unsigned short* __restrict__ peb) {
    const int i = blockIdx.x * 256 + threadIdx.x;    // 131072 threads x float4
    const float4 v = ((const float4*)pe)[i];
    const unsigned lo = (unsigned)f2bf(v.x) | ((unsigned)f2bf(v.y) << 16);
    const unsigned hi = (unsigned)f2bf(v.z) | ((unsigned)f2bf(v.w) << 16);
    ((uint2*)peb)[i] = make_uint2(lo, hi);
}

// ---------------- Kernel B: MFMA flash attention -----------------------------
// Block: 4 waves, 64-row t-tile (16-row strip per wave), s-tiles of 64.
// Scores: S = Q@K^T (4 MFMA) + skew gather from R = Q@pe_band^T (5 MFMA).
// Online softmax in registers (C-layout rows live in quads). PV via LDS P.
__global__ __launch_bounds__(256) void attn_kernel(const unsigned short* __restrict__ Kb,
                                                   const unsigned short* __restrict__ Qb,
                                                   const unsigned short* __restrict__ Vtg,
                                                   const unsigned short* __restrict__ peb,
                                                   float* __restrict__ att) {
    __shared__ unsigned short lds[14592];            // 29184 B
    unsigned short* Ks  = lds;                       // [64][40]  K tile
    unsigned short* PEs = lds + 2560;                // [128][40] pe band
    unsigned short* Vts = lds + 7680;                // [32][72]  V^T tile
    unsigned short* Psw = lds + 9984 + (threadIdx.x >> 6) * 1152;  // [16][72] per wave

    const int tid = threadIdx.x;
    const int wv  = tid >> 6;
    const int L   = tid & 63;
    const int l15 = L & 15;
    const int q   = L >> 4;
    const int h = blockIdx.y, b = blockIdx.z;
    const long bh = (long)b * NH + h;
    const unsigned short* Kg = Kb  + bh * TT * HD;
    const unsigned short* Qg = Qb  + bh * TT * HD;
    const unsigned short* Vg = Vtg + bh * HD * TT;
    const unsigned short* Pg = peb + (long)h * TT * HD;

    const int krow = tid >> 2, kc = tid & 3;         // K/PE staging split
    const int vrow = tid >> 3, vc = tid & 7;         // V^T staging split
    const f4 z4 = {0.f, 0.f, 0.f, 0.f};

    for (int half = 0; half < 2; ++half) {
        const int itile = half ? 31 - (int)blockIdx.x : (int)blockIdx.x;
        const int t0 = itile * 64;

        const bf8 aq = *(const bf8*)(Qg + (t0 + wv * 16 + l15) * HD + q * 8);
        f4 o0 = z4, o1 = z4;
        float m_st[4] = {-1e30f, -1e30f, -1e30f, -1e30f};
        float l_st[4] = {0.f, 0.f, 0.f, 0.f};

        for (int jt = 0; jt <= itile; ++jt) {
            const int s0 = jt * 64;
            const int ubase = TT - 64 - t0 + s0;     // pe band base (>= 0)
            __syncthreads();                         // prior reads done
            *(bf8*)(Ks  + krow * 40 + kc * 8) = *(const bf8*)(Kg + (s0 + krow) * HD + kc * 8);
            *(bf8*)(Vts + vrow * 72 + vc * 8) = *(const bf8*)(Vg + vrow * TT + s0 + vc * 8);
            #pragma unroll
            for (int kk = 0; kk < 2; ++kk) {
                const int i  = tid + kk * 256;
                const int pr = i >> 2, pc = i & 3;
                const int u  = ubase + pr;
                bf8 val = {0,0,0,0,0,0,0,0};
                if (u < TT) val = *(const bf8*)(Pg + (long)u * HD + pc * 8);
                *(bf8*)(PEs + pr * 40 + pc * 8) = val;
            }
            __syncthreads();

            // ---- QK^T (4 n-tiles) + Q.pe band (5 n-tiles) ----
            f4 sa[4], ra[5];
            #pragma unroll
            for (int nt = 0; nt < 4; ++nt) {
                const bf8 bk = *(const bf8*)(Ks + (nt * 16 + l15) * 40 + q * 8);
                sa[nt] = __builtin_amdgcn_mfma_f32_16x16x32_bf16(aq, bk, z4, 0, 0, 0);
            }
            const int pebase = 48 - 16 * wv;         // strip's band offset in PEs
            #pragma unroll
            for (int nt = 0; nt < 5; ++nt) {
                const bf8 bp = *(const bf8*)(PEs + (pebase + nt * 16 + l15) * 40 + q * 8);
                ra[nt] = __builtin_amdgcn_mfma_f32_16x16x32_bf16(aq, bp, z4, 0, 0, 0);
            }

            // ---- skew gather: S2[t,s] = R[t, 15 + s - t] (rotate in quad) ----
            #pragma unroll
            for (int nb = 0; nb < 4; ++nb) {
                #pragma unroll
                for (int r = 0; r < 4; ++r) {
                    const int shift = 15 - 4 * q - r;          // 0..15
                    const int tcol  = l15 + shift;             // 0..30
                    const int src   = (q << 4) | (tcol & 15);
                    const float va = __shfl(ra[nb][r], src);
                    const float vb = __shfl(ra[nb + 1][r], src);
                    sa[nb][r] += (tcol < 16) ? va : vb;
                }
            }

            // ---- causal mask (diagonal tile only) ----
            if (jt == itile) {
                #pragma unroll
                for (int nb = 0; nb < 4; ++nb)
                    #pragma unroll
                    for (int r = 0; r < 4; ++r) {
                        const int s_l = nb * 16 + l15;
                        const int t_l = wv * 16 + 4 * q + r;
                        if (s_l > t_l) sa[nb][r] = -1e30f;
                    }
            }

            // ---- online softmax: rows 4q+r owned by quad q ----
            float corr[4];
            #pragma unroll
            for (int r = 0; r < 4; ++r) {
                float mx = fmaxf(fmaxf(sa[0][r], sa[1][r]), fmaxf(sa[2][r], sa[3][r]));
                mx = fmaxf(mx, __shfl_xor(mx, 1));
                mx = fmaxf(mx, __shfl_xor(mx, 2));
                mx = fmaxf(mx, __shfl_xor(mx, 4));
                mx = fmaxf(mx, __shfl_xor(mx, 8));
                const float mn = fmaxf(m_st[r], mx);
                corr[r] = __expf(m_st[r] - mn);
                m_st[r] = mn;
                float rs = 0.f;
                #pragma unroll
                for (int nb = 0; nb < 4; ++nb) {
                    const float p = __expf(sa[nb][r] - mn);
                    rs += p;
                    Psw[(4 * q + r) * 72 + nb * 16 + l15] = f2bf(p);
                }
                rs += __shfl_xor(rs, 1); rs += __shfl_xor(rs, 2);
                rs += __shfl_xor(rs, 4); rs += __shfl_xor(rs, 8);
                l_st[r] = l_st[r] * corr[r] + rs;
            }
            #pragma unroll
            for (int r = 0; r < 4; ++r) { o0[r] *= corr[r]; o1[r] *= corr[r]; }

            // ---- PV: O += P @ V (A from LDS round-trip, B from V^T tile) ----
            #pragma unroll
            for (int ks = 0; ks < 2; ++ks) {
                const bf8 ap  = *(const bf8*)(Psw + l15 * 72 + ks * 32 + q * 8);
                const bf8 bv0 = *(const bf8*)(Vts + l15 * 72 + ks * 32 + q * 8);
                const bf8 bv1 = *(const bf8*)(Vts + (16 + l15) * 72 + ks * 32 + q * 8);
                o0 = __builtin_amdgcn_mfma_f32_16x16x32_bf16(ap, bv0, o0, 0, 0, 0);
                o1 = __builtin_amdgcn_mfma_f32_16x16x32_bf16(ap, bv1, o1, 0, 0, 0);
            }
        }

        // ---- epilogue: normalize, store fp32 att ----
        #pragma unroll
        for (int r = 0; r < 4; ++r) {
            const float inv = 1.0f / l_st[r];
            const int t = t0 + wv * 16 + 4 * q + r;
            float* dst = att + ((long)(b * TT + t)) * NEMB + h * HD;
            dst[l15]      = o0[r] * inv;
            dst[16 + l15] = o1[r] * inv;
        }
    }
}

// ---------------- Kernel C: out = att @ w_proj + b_proj ----------------------
__global__ __launch_bounds__(256) void proj_gemm(const float* __restrict__ att,
                                                 const float* __restrict__ w,
                                                 const float* __restrict__ bias,
                                                 float* __restrict__ out) {
    const int c  = threadIdx.x;          // 0..255
    const int r0 = blockIdx.x * 8;
    float acc[8] = {0.f,0.f,0.f,0.f,0.f,0.f,0.f,0.f};
    const float* arow = att + (long)r0 * NEMB;
    #pragma unroll 4
    for (int k = 0; k < NEMB; ++k) {
        const float wvv = w[k * NEMB + c];
        #pragma unroll
        for (int i = 0; i < 8; ++i)
            acc[i] += arow[i * NEMB + k] * wvv;
    }
    const float bv = bias[c];
    #pragma unroll
    for (int i = 0; i < 8; ++i)
        out[(long)(r0 + i) * NEMB + c] = acc[i] + bv;
}

extern "C" void kernel_launch(void* const* d_in, const int* in_sizes, int n_in,
                              void* d_out, int out_size, void* d_ws, size_t ws_size,
                              hipStream_t stream) {
    const float* x      = (const float*)d_in[0];
    const float* w_attn = (const float*)d_in[1];
    const float* pe     = (const float*)d_in[2];
    const float* w_proj = (const float*)d_in[3];
    const float* b_proj = (const float*)d_in[4];
    float* out = (float*)d_out;

    char* base = (char*)d_ws;
    unsigned short* Kb  = (unsigned short*)(base);                 // 4 MB
    unsigned short* Qb  = (unsigned short*)(base + (4u << 20));    // 4 MB
    unsigned short* Vt  = (unsigned short*)(base + (8u << 20));    // 4 MB
    unsigned short* peb = (unsigned short*)(base + (12u << 20));   // 1 MB
    float*          att = (float*)        (base + (13u << 20));    // 8 MB

    qkv_gemm<<<dim3(3, 1024), 256, 0, stream>>>(x, w_attn, Kb, Qb, Vt);
    pe_cvt<<<dim3(512), 256, 0, stream>>>(pe, peb);
    attn_kernel<<<dim3(16, NH, BB), 256, 0, stream>>>(Kb, Qb, Vt, peb, att);
    proj_gemm<<<dim3(1024), 256, 0, stream>>>(att, w_proj, b_proj, out);
}

// Round 4
// 177.919 us; speedup vs baseline: 17.2052x; 1.4726x over previous
//
#include <hip/hip_runtime.h>
#include <math.h>

#define BB 4
#define TT 2048
#define NEMB 256
#define NH 8
#define HD 32

typedef __attribute__((ext_vector_type(8))) short bf8;   // 8 x bf16 (4 VGPRs)
typedef __attribute__((ext_vector_type(4))) float f4;    // MFMA C/D

static __device__ __forceinline__ unsigned short f2bf(float f) {
    union { float f; unsigned u; } v; v.f = f;
    unsigned r = v.u + 0x7FFF + ((v.u >> 16) & 1);       // RNE
    return (unsigned short)(r >> 16);
}

// ---------------- x -> bf16 --------------------------------------------------
__global__ __launch_bounds__(256) void xcvt(const float* __restrict__ x,
                                            unsigned short* __restrict__ xb) {
    const long i = (long)blockIdx.x * 256 + threadIdx.x;
    const float4 v = ((const float4*)x)[i];
    ushort4 o; o.x = f2bf(v.x); o.y = f2bf(v.y); o.z = f2bf(v.z); o.w = f2bf(v.w);
    ((ushort4*)xb)[i] = o;
}

// ---------------- transpose-convert: src[R][C] fp32 -> dst[C][R] bf16 --------
__global__ __launch_bounds__(256) void tcvt(const float* __restrict__ src,
                                            unsigned short* __restrict__ dst,
                                            int R, int C) {
    __shared__ float t[64][65];
    const int tid = threadIdx.x;
    const int c0 = blockIdx.x * 64, r0 = blockIdx.y * 64;
    #pragma unroll
    for (int p = 0; p < 4; ++p) {
        const int i = tid + p * 256;
        const int r = i >> 4, c4 = (i & 15) * 4;
        const float4 v = *(const float4*)(src + (long)(r0 + r) * C + c0 + c4);
        t[r][c4] = v.x; t[r][c4+1] = v.y; t[r][c4+2] = v.z; t[r][c4+3] = v.w;
    }
    __syncthreads();
    #pragma unroll
    for (int p = 0; p < 4; ++p) {
        const int i = tid + p * 256;
        const int cr = i >> 4, r4 = (i & 15) * 4;
        ushort4 vv;
        vv.x = f2bf(t[r4+0][cr]); vv.y = f2bf(t[r4+1][cr]);
        vv.z = f2bf(t[r4+2][cr]); vv.w = f2bf(t[r4+3][cr]);
        *(ushort4*)(dst + (long)(c0 + cr) * R + r0 + r4) = vv;
    }
}

// ---------------- pe -> bf16 -------------------------------------------------
__global__ __launch_bounds__(256) void pe_cvt(const float* __restrict__ pe,
                                              unsigned short* __restrict__ peb) {
    const int i = blockIdx.x * 256 + threadIdx.x;
    const float4 v = ((const float4*)pe)[i];
    ushort4 o; o.x = f2bf(v.x); o.y = f2bf(v.y); o.z = f2bf(v.z); o.w = f2bf(v.w);
    ((ushort4*)peb)[i] = o;
}

// ---------------- Kernel A: MFMA qkv GEMM + packed epilogue ------------------
// A = xb [8192][256] bf16, B = waT [768][256] bf16. 128x64 tile per block.
__global__ __launch_bounds__(256) void qkv_mfma(const unsigned short* __restrict__ Ag,
                                                const unsigned short* __restrict__ Bg,
                                                unsigned short* __restrict__ Kb,
                                                unsigned short* __restrict__ Qb,
                                                unsigned short* __restrict__ Vt) {
    __shared__ unsigned short sm[13824];             // 27648 B
    unsigned short* As = sm;                         // [128][72]
    unsigned short* Bs = sm + 9216;                  // [64][72]
    const int tid = threadIdx.x;
    const int wv = tid >> 6, L = tid & 63;
    const int l15 = L & 15, q = L >> 4;
    const int n0 = blockIdx.x * 64;
    const int m0 = blockIdx.y * 128;

    f4 acc[2][4];
    #pragma unroll
    for (int mt = 0; mt < 2; ++mt)
        #pragma unroll
        for (int nt = 0; nt < 4; ++nt) acc[mt][nt] = (f4){0.f,0.f,0.f,0.f};

    for (int kc = 0; kc < 4; ++kc) {
        const int k0 = kc * 64;
        __syncthreads();
        #pragma unroll
        for (int p = 0; p < 4; ++p) {
            const int i = tid + p * 256;
            const int r = i >> 3, c = i & 7;
            *(bf8*)(As + r * 72 + c * 8) = *(const bf8*)(Ag + (long)(m0 + r) * 256 + k0 + c * 8);
        }
        #pragma unroll
        for (int p = 0; p < 2; ++p) {
            const int i = tid + p * 256;
            const int r = i >> 3, c = i & 7;
            *(bf8*)(Bs + r * 72 + c * 8) = *(const bf8*)(Bg + (long)(n0 + r) * 256 + k0 + c * 8);
        }
        __syncthreads();
        #pragma unroll
        for (int kk = 0; kk < 2; ++kk) {
            const bf8 a0 = *(const bf8*)(As + (wv * 32 + l15) * 72 + kk * 32 + q * 8);
            const bf8 a1 = *(const bf8*)(As + (wv * 32 + 16 + l15) * 72 + kk * 32 + q * 8);
            #pragma unroll
            for (int nt = 0; nt < 4; ++nt) {
                const bf8 bb = *(const bf8*)(Bs + (nt * 16 + l15) * 72 + kk * 32 + q * 8);
                acc[0][nt] = __builtin_amdgcn_mfma_f32_16x16x32_bf16(a0, bb, acc[0][nt], 0, 0, 0);
                acc[1][nt] = __builtin_amdgcn_mfma_f32_16x16x32_bf16(a1, bb, acc[1][nt], 0, 0, 0);
            }
        }
    }

    const int sec = n0 >> 8;                         // 0=K,1=Q,2=V (block-uniform)
    #pragma unroll
    for (int mt = 0; mt < 2; ++mt) {
        const int gm = m0 + wv * 32 + mt * 16 + q * 4;
        const int b = gm >> 11, tb = gm & 2047;
        #pragma unroll
        for (int nt = 0; nt < 4; ++nt) {
            const int gn = n0 + nt * 16 + l15;
            const int cc = gn & 255, h = cc >> 5, d = cc & 31;
            const long bh = (long)b * NH + h;
            const f4 a = acc[mt][nt];
            if (sec == 2) {
                ushort4 vv;
                vv.x = f2bf(a[0]); vv.y = f2bf(a[1]); vv.z = f2bf(a[2]); vv.w = f2bf(a[3]);
                *(ushort4*)(Vt + (bh * HD + d) * TT + tb) = vv;
            } else if (sec == 1) {
                #pragma unroll
                for (int r = 0; r < 4; ++r)
                    Qb[(bh * TT + tb + r) * HD + d] = f2bf(a[r] * 0.17677669529663687f);
            } else {
                #pragma unroll
                for (int r = 0; r < 4; ++r)
                    Kb[(bh * TT + tb + r) * HD + d] = f2bf(a[r]);
            }
        }
    }
}

// ---------------- Kernel B: MFMA flash attention (bf16 out) ------------------
__global__ __launch_bounds__(256) void attn_kernel(const unsigned short* __restrict__ Kb,
                                                   const unsigned short* __restrict__ Qb,
                                                   const unsigned short* __restrict__ Vtg,
                                                   const unsigned short* __restrict__ peb,
                                                   unsigned short* __restrict__ att) {
    __shared__ unsigned short lds[14592];            // 29184 B
    unsigned short* Ks  = lds;                       // [64][40]  K tile
    unsigned short* PEs = lds + 2560;                // [128][40] pe band
    unsigned short* Vts = lds + 7680;                // [32][72]  V^T tile
    unsigned short* Psw = lds + 9984 + (threadIdx.x >> 6) * 1152;  // [16][72] per wave

    const int tid = threadIdx.x;
    const int wv  = tid >> 6;
    const int L   = tid & 63;
    const int l15 = L & 15;
    const int q   = L >> 4;
    const int h = blockIdx.y, b = blockIdx.z;
    const long bh = (long)b * NH + h;
    const unsigned short* Kg = Kb  + bh * TT * HD;
    const unsigned short* Qg = Qb  + bh * TT * HD;
    const unsigned short* Vg = Vtg + bh * HD * TT;
    const unsigned short* Pg = peb + (long)h * TT * HD;

    const int krow = tid >> 2, kc = tid & 3;
    const int vrow = tid >> 3, vc = tid & 7;
    const f4 z4 = {0.f, 0.f, 0.f, 0.f};

    for (int half = 0; half < 2; ++half) {
        const int itile = half ? 31 - (int)blockIdx.x : (int)blockIdx.x;
        const int t0 = itile * 64;

        const bf8 aq = *(const bf8*)(Qg + (t0 + wv * 16 + l15) * HD + q * 8);
        f4 o0 = z4, o1 = z4;
        float m_st[4] = {-1e30f, -1e30f, -1e30f, -1e30f};
        float l_st[4] = {0.f, 0.f, 0.f, 0.f};

        for (int jt = 0; jt <= itile; ++jt) {
            const int s0 = jt * 64;
            const int ubase = TT - 64 - t0 + s0;
            __syncthreads();
            *(bf8*)(Ks  + krow * 40 + kc * 8) = *(const bf8*)(Kg + (s0 + krow) * HD + kc * 8);
            *(bf8*)(Vts + vrow * 72 + vc * 8) = *(const bf8*)(Vg + vrow * TT + s0 + vc * 8);
            #pragma unroll
            for (int kk = 0; kk < 2; ++kk) {
                const int i  = tid + kk * 256;
                const int pr = i >> 2, pc = i & 3;
                const int u  = ubase + pr;
                bf8 val = {0,0,0,0,0,0,0,0};
                if (u < TT) val = *(const bf8*)(Pg + (long)u * HD + pc * 8);
                *(bf8*)(PEs + pr * 40 + pc * 8) = val;
            }
            __syncthreads();

            f4 sa[4], ra[5];
            #pragma unroll
            for (int nt = 0; nt < 4; ++nt) {
                const bf8 bk = *(const bf8*)(Ks + (nt * 16 + l15) * 40 + q * 8);
                sa[nt] = __builtin_amdgcn_mfma_f32_16x16x32_bf16(aq, bk, z4, 0, 0, 0);
            }
            const int pebase = 48 - 16 * wv;
            #pragma unroll
            for (int nt = 0; nt < 5; ++nt) {
                const bf8 bp = *(const bf8*)(PEs + (pebase + nt * 16 + l15) * 40 + q * 8);
                ra[nt] = __builtin_amdgcn_mfma_f32_16x16x32_bf16(aq, bp, z4, 0, 0, 0);
            }

            #pragma unroll
            for (int nb = 0; nb < 4; ++nb) {
                #pragma unroll
                for (int r = 0; r < 4; ++r) {
                    const int shift = 15 - 4 * q - r;
                    const int tcol  = l15 + shift;
                    const int src   = (q << 4) | (tcol & 15);
                    const float va = __shfl(ra[nb][r], src);
                    const float vb = __shfl(ra[nb + 1][r], src);
                    sa[nb][r] += (tcol < 16) ? va : vb;
                }
            }

            if (jt == itile) {
                #pragma unroll
                for (int nb = 0; nb < 4; ++nb)
                    #pragma unroll
                    for (int r = 0; r < 4; ++r) {
                        const int s_l = nb * 16 + l15;
                        const int t_l = wv * 16 + 4 * q + r;
                        if (s_l > t_l) sa[nb][r] = -1e30f;
                    }
            }

            float corr[4];
            #pragma unroll
            for (int r = 0; r < 4; ++r) {
                float mx = fmaxf(fmaxf(sa[0][r], sa[1][r]), fmaxf(sa[2][r], sa[3][r]));
                mx = fmaxf(mx, __shfl_xor(mx, 1));
                mx = fmaxf(mx, __shfl_xor(mx, 2));
                mx = fmaxf(mx, __shfl_xor(mx, 4));
                mx = fmaxf(mx, __shfl_xor(mx, 8));
                const float mn = fmaxf(m_st[r], mx);
                corr[r] = __expf(m_st[r] - mn);
                m_st[r] = mn;
                float rs = 0.f;
                #pragma unroll
                for (int nb = 0; nb < 4; ++nb) {
                    const float p = __expf(sa[nb][r] - mn);
                    rs += p;
                    Psw[(4 * q + r) * 72 + nb * 16 + l15] = f2bf(p);
                }
                rs += __shfl_xor(rs, 1); rs += __shfl_xor(rs, 2);
                rs += __shfl_xor(rs, 4); rs += __shfl_xor(rs, 8);
                l_st[r] = l_st[r] * corr[r] + rs;
            }
            #pragma unroll
            for (int r = 0; r < 4; ++r) { o0[r] *= corr[r]; o1[r] *= corr[r]; }

            #pragma unroll
            for (int ks = 0; ks < 2; ++ks) {
                const bf8 ap  = *(const bf8*)(Psw + l15 * 72 + ks * 32 + q * 8);
                const bf8 bv0 = *(const bf8*)(Vts + l15 * 72 + ks * 32 + q * 8);
                const bf8 bv1 = *(const bf8*)(Vts + (16 + l15) * 72 + ks * 32 + q * 8);
                o0 = __builtin_amdgcn_mfma_f32_16x16x32_bf16(ap, bv0, o0, 0, 0, 0);
                o1 = __builtin_amdgcn_mfma_f32_16x16x32_bf16(ap, bv1, o1, 0, 0, 0);
            }
        }

        #pragma unroll
        for (int r = 0; r < 4; ++r) {
            const float inv = 1.0f / l_st[r];
            const int t = t0 + wv * 16 + 4 * q + r;
            unsigned short* dst = att + ((long)(b * TT + t)) * NEMB + h * HD;
            dst[l15]      = f2bf(o0[r] * inv);
            dst[16 + l15] = f2bf(o1[r] * inv);
        }
    }
}

// ---------------- Kernel C: MFMA proj GEMM + bias ----------------------------
// A = attb [8192][256] bf16, B = wpT [256][256] bf16, out fp32 + bias.
__global__ __launch_bounds__(256) void proj_mfma(const unsigned short* __restrict__ Ag,
                                                 const unsigned short* __restrict__ Bg,
                                                 const float* __restrict__ bias,
                                                 float* __restrict__ out) {
    __shared__ unsigned short sm[13824];
    unsigned short* As = sm;                         // [128][72]
    unsigned short* Bs = sm + 9216;                  // [64][72]
    const int tid = threadIdx.x;
    const int wv = tid >> 6, L = tid & 63;
    const int l15 = L & 15, q = L >> 4;
    const int n0 = blockIdx.x * 64;
    const int m0 = blockIdx.y * 128;

    f4 acc[2][4];
    #pragma unroll
    for (int mt = 0; mt < 2; ++mt)
        #pragma unroll
        for (int nt = 0; nt < 4; ++nt) acc[mt][nt] = (f4){0.f,0.f,0.f,0.f};

    for (int kc = 0; kc < 4; ++kc) {
        const int k0 = kc * 64;
        __syncthreads();
        #pragma unroll
        for (int p = 0; p < 4; ++p) {
            const int i = tid + p * 256;
            const int r = i >> 3, c = i & 7;
            *(bf8*)(As + r * 72 + c * 8) = *(const bf8*)(Ag + (long)(m0 + r) * 256 + k0 + c * 8);
        }
        #pragma unroll
        for (int p = 0; p < 2; ++p) {
            const int i = tid + p * 256;
            const int r = i >> 3, c = i & 7;
            *(bf8*)(Bs + r * 72 + c * 8) = *(const bf8*)(Bg + (long)(n0 + r) * 256 + k0 + c * 8);
        }
        __syncthreads();
        #pragma unroll
        for (int kk = 0; kk < 2; ++kk) {
            const bf8 a0 = *(const bf8*)(As + (wv * 32 + l15) * 72 + kk * 32 + q * 8);
            const bf8 a1 = *(const bf8*)(As + (wv * 32 + 16 + l15) * 72 + kk * 32 + q * 8);
            #pragma unroll
            for (int nt = 0; nt < 4; ++nt) {
                const bf8 bb = *(const bf8*)(Bs + (nt * 16 + l15) * 72 + kk * 32 + q * 8);
                acc[0][nt] = __builtin_amdgcn_mfma_f32_16x16x32_bf16(a0, bb, acc[0][nt], 0, 0, 0);
                acc[1][nt] = __builtin_amdgcn_mfma_f32_16x16x32_bf16(a1, bb, acc[1][nt], 0, 0, 0);
            }
        }
    }

    #pragma unroll
    for (int mt = 0; mt < 2; ++mt) {
        const int gm = m0 + wv * 32 + mt * 16 + q * 4;
        #pragma unroll
        for (int nt = 0; nt < 4; ++nt) {
            const int gn = n0 + nt * 16 + l15;
            const float bv = bias[gn];
            #pragma unroll
            for (int r = 0; r < 4; ++r)
                out[(long)(gm + r) * NEMB + gn] = acc[mt][nt][r] + bv;
        }
    }
}

extern "C" void kernel_launch(void* const* d_in, const int* in_sizes, int n_in,
                              void* d_out, int out_size, void* d_ws, size_t ws_size,
                              hipStream_t stream) {
    const float* x      = (const float*)d_in[0];
    const float* w_attn = (const float*)d_in[1];
    const float* pe     = (const float*)d_in[2];
    const float* w_proj = (const float*)d_in[3];
    const float* b_proj = (const float*)d_in[4];
    float* out = (float*)d_out;

    char* base = (char*)d_ws;
    unsigned short* xb   = (unsigned short*)(base);                    // 4 MB
    unsigned short* Kb   = (unsigned short*)(base + ( 4u << 20));      // 4 MB
    unsigned short* Qb   = (unsigned short*)(base + ( 8u << 20));      // 4 MB
    unsigned short* Vt   = (unsigned short*)(base + (12u << 20));      // 4 MB
    unsigned short* attb = (unsigned short*)(base + (16u << 20));      // 4 MB
    unsigned short* peb  = (unsigned short*)(base + (20u << 20));      // 1 MB
    unsigned short* waT  = (unsigned short*)(base + (21u << 20));      // 384 KB
    unsigned short* wpT  = (unsigned short*)(base + (22u << 20));      // 128 KB

    xcvt<<<dim3(2048), 256, 0, stream>>>(x, xb);
    tcvt<<<dim3(12, 4), 256, 0, stream>>>(w_attn, waT, NEMB, 768);
    tcvt<<<dim3(4, 4), 256, 0, stream>>>(w_proj, wpT, NEMB, NEMB);
    pe_cvt<<<dim3(512), 256, 0, stream>>>(pe, peb);
    qkv_mfma<<<dim3(12, 64), 256, 0, stream>>>(xb, waT, Kb, Qb, Vt);
    attn_kernel<<<dim3(16, NH, BB), 256, 0, stream>>>(Kb, Qb, Vt, peb, attb);
    proj_mfma<<<dim3(4, 64), 256, 0, stream>>>(attb, wpT, b_proj, out);
}

// Round 5
// 169.072 us; speedup vs baseline: 18.1054x; 1.0523x over previous
//
#include <hip/hip_runtime.h>
#include <math.h>

#define BB 4
#define TT 2048
#define NEMB 256
#define NH 8
#define HD 32

typedef __attribute__((ext_vector_type(8))) short bf8;   // 8 x bf16 (4 VGPRs)
typedef __attribute__((ext_vector_type(4))) float f4;    // MFMA C/D

static __device__ __forceinline__ unsigned short f2bf(float f) {
    union { float f; unsigned u; } v; v.f = f;
    unsigned r = v.u + 0x7FFF + ((v.u >> 16) & 1);       // RNE
    return (unsigned short)(r >> 16);
}

// DPP cross-lane move within 16-lane rows (VALU pipe, not LDS pipe)
template <int CTRL>
static __device__ __forceinline__ float dppmv(float x) {
    return __int_as_float(__builtin_amdgcn_mov_dpp(__float_as_int(x), CTRL, 0xF, 0xF, true));
}
// reduce across the 16 lanes of each DPP row: quad_perm xor1, xor2, row_ror 4, 8
static __device__ __forceinline__ float rowmax16(float x) {
    x = fmaxf(x, dppmv<0xB1>(x));
    x = fmaxf(x, dppmv<0x4E>(x));
    x = fmaxf(x, dppmv<0x124>(x));
    x = fmaxf(x, dppmv<0x128>(x));
    return x;
}
static __device__ __forceinline__ float rowsum16(float x) {
    x += dppmv<0xB1>(x);
    x += dppmv<0x4E>(x);
    x += dppmv<0x124>(x);
    x += dppmv<0x128>(x);
    return x;
}

// ---------------- fused prep: x->bf16, pe->bf16, w_attn^T, w_proj^T ----------
static __device__ __forceinline__ void tcvt_body(const float* __restrict__ src,
                                                 unsigned short* __restrict__ dst,
                                                 int R, int C, int gx, int gy,
                                                 float (*t)[65], int tid) {
    const int c0 = gx * 64, r0 = gy * 64;
    #pragma unroll
    for (int p = 0; p < 4; ++p) {
        const int i = tid + p * 256;
        const int r = i >> 4, c4 = (i & 15) * 4;
        const float4 v = *(const float4*)(src + (long)(r0 + r) * C + c0 + c4);
        t[r][c4] = v.x; t[r][c4+1] = v.y; t[r][c4+2] = v.z; t[r][c4+3] = v.w;
    }
    __syncthreads();
    #pragma unroll
    for (int p = 0; p < 4; ++p) {
        const int i = tid + p * 256;
        const int cr = i >> 4, r4 = (i & 15) * 4;
        ushort4 vv;
        vv.x = f2bf(t[r4+0][cr]); vv.y = f2bf(t[r4+1][cr]);
        vv.z = f2bf(t[r4+2][cr]); vv.w = f2bf(t[r4+3][cr]);
        *(ushort4*)(dst + (long)(c0 + cr) * R + r0 + r4) = vv;
    }
}

__global__ __launch_bounds__(256) void prep(const float* __restrict__ x,
                                            unsigned short* __restrict__ xb,
                                            const float* __restrict__ pe,
                                            unsigned short* __restrict__ peb,
                                            const float* __restrict__ wa,
                                            unsigned short* __restrict__ waT,
                                            const float* __restrict__ wp,
                                            unsigned short* __restrict__ wpT) {
    __shared__ float t[64][65];
    const int bx = blockIdx.x, tid = threadIdx.x;
    if (bx < 2048) {
        const long i = (long)bx * 256 + tid;
        const float4 v = ((const float4*)x)[i];
        ushort4 o; o.x = f2bf(v.x); o.y = f2bf(v.y); o.z = f2bf(v.z); o.w = f2bf(v.w);
        ((ushort4*)xb)[i] = o;
    } else if (bx < 2560) {
        const long i = (long)(bx - 2048) * 256 + tid;
        const float4 v = ((const float4*)pe)[i];
        ushort4 o; o.x = f2bf(v.x); o.y = f2bf(v.y); o.z = f2bf(v.z); o.w = f2bf(v.w);
        ((ushort4*)peb)[i] = o;
    } else if (bx < 2608) {
        const int lo = bx - 2560;                 // 48 blocks: w_attn [256][768] -> [768][256]
        tcvt_body(wa, waT, 256, 768, lo % 12, lo / 12, t, tid);
    } else {
        const int lo = bx - 2608;                 // 16 blocks: w_proj [256][256] -> [256][256]^T
        tcvt_body(wp, wpT, 256, 256, lo % 4, lo / 4, t, tid);
    }
}

// ---------------- Kernel A: MFMA qkv GEMM + packed epilogue ------------------
// A = xb [8192][256] bf16, B = waT [768][256] bf16. 128x64 tile per block.
// Q is pre-scaled by (1/sqrt(32)) * log2(e) so attention can use exp2.
__global__ __launch_bounds__(256) void qkv_mfma(const unsigned short* __restrict__ Ag,
                                                const unsigned short* __restrict__ Bg,
                                                unsigned short* __restrict__ Kb,
                                                unsigned short* __restrict__ Qb,
                                                unsigned short* __restrict__ Vt) {
    __shared__ unsigned short sm[13824];             // 27648 B
    unsigned short* As = sm;                         // [128][72]
    unsigned short* Bs = sm + 9216;                  // [64][72]
    const int tid = threadIdx.x;
    const int wv = tid >> 6, L = tid & 63;
    const int l15 = L & 15, q = L >> 4;
    const int n0 = blockIdx.x * 64;
    const int m0 = blockIdx.y * 128;

    f4 acc[2][4];
    #pragma unroll
    for (int mt = 0; mt < 2; ++mt)
        #pragma unroll
        for (int nt = 0; nt < 4; ++nt) acc[mt][nt] = (f4){0.f,0.f,0.f,0.f};

    for (int kc = 0; kc < 4; ++kc) {
        const int k0 = kc * 64;
        __syncthreads();
        #pragma unroll
        for (int p = 0; p < 4; ++p) {
            const int i = tid + p * 256;
            const int r = i >> 3, c = i & 7;
            *(bf8*)(As + r * 72 + c * 8) = *(const bf8*)(Ag + (long)(m0 + r) * 256 + k0 + c * 8);
        }
        #pragma unroll
        for (int p = 0; p < 2; ++p) {
            const int i = tid + p * 256;
            const int r = i >> 3, c = i & 7;
            *(bf8*)(Bs + r * 72 + c * 8) = *(const bf8*)(Bg + (long)(n0 + r) * 256 + k0 + c * 8);
        }
        __syncthreads();
        #pragma unroll
        for (int kk = 0; kk < 2; ++kk) {
            const bf8 a0 = *(const bf8*)(As + (wv * 32 + l15) * 72 + kk * 32 + q * 8);
            const bf8 a1 = *(const bf8*)(As + (wv * 32 + 16 + l15) * 72 + kk * 32 + q * 8);
            #pragma unroll
            for (int nt = 0; nt < 4; ++nt) {
                const bf8 bb = *(const bf8*)(Bs + (nt * 16 + l15) * 72 + kk * 32 + q * 8);
                acc[0][nt] = __builtin_amdgcn_mfma_f32_16x16x32_bf16(a0, bb, acc[0][nt], 0, 0, 0);
                acc[1][nt] = __builtin_amdgcn_mfma_f32_16x16x32_bf16(a1, bb, acc[1][nt], 0, 0, 0);
            }
        }
    }

    const int sec = n0 >> 8;                         // 0=K,1=Q,2=V (block-uniform)
    #pragma unroll
    for (int mt = 0; mt < 2; ++mt) {
        const int gm = m0 + wv * 32 + mt * 16 + q * 4;
        const int b = gm >> 11, tb = gm & 2047;
        #pragma unroll
        for (int nt = 0; nt < 4; ++nt) {
            const int gn = n0 + nt * 16 + l15;
            const int cc = gn & 255, h = cc >> 5, d = cc & 31;
            const long bh = (long)b * NH + h;
            const f4 a = acc[mt][nt];
            if (sec == 2) {
                ushort4 vv;
                vv.x = f2bf(a[0]); vv.y = f2bf(a[1]); vv.z = f2bf(a[2]); vv.w = f2bf(a[3]);
                *(ushort4*)(Vt + (bh * HD + d) * TT + tb) = vv;
            } else if (sec == 1) {
                #pragma unroll
                for (int r = 0; r < 4; ++r)
                    Qb[(bh * TT + tb + r) * HD + d] = f2bf(a[r] * 0.25506655788696527f);
            } else {
                #pragma unroll
                for (int r = 0; r < 4; ++r)
                    Kb[(bh * TT + tb + r) * HD + d] = f2bf(a[r]);
            }
        }
    }
}

// ---------------- Kernel B: MFMA flash attention (bf16 out) ------------------
__global__ __launch_bounds__(256) void attn_kernel(const unsigned short* __restrict__ Kb,
                                                   const unsigned short* __restrict__ Qb,
                                                   const unsigned short* __restrict__ Vtg,
                                                   const unsigned short* __restrict__ peb,
                                                   unsigned short* __restrict__ att) {
    __shared__ unsigned short lds[14592];            // 29184 B
    unsigned short* Ks  = lds;                       // [64][40]  K tile
    unsigned short* PEs = lds + 2560;                // [128][40] pe band
    unsigned short* Vts = lds + 7680;                // [32][72]  V^T tile
    unsigned short* Psw = lds + 9984 + (threadIdx.x >> 6) * 1152;  // [16][72] per wave

    const int tid = threadIdx.x;
    const int wv  = tid >> 6;
    const int L   = tid & 63;
    const int l15 = L & 15;
    const int q   = L >> 4;
    const int h = blockIdx.y, b = blockIdx.z;
    const long bh = (long)b * NH + h;
    const unsigned short* Kg = Kb  + bh * TT * HD;
    const unsigned short* Qg = Qb  + bh * TT * HD;
    const unsigned short* Vg = Vtg + bh * HD * TT;
    const unsigned short* Pg = peb + (long)h * TT * HD;

    const int krow = tid >> 2, kc = tid & 3;
    const int vrow = tid >> 3, vc = tid & 7;
    const f4 z4 = {0.f, 0.f, 0.f, 0.f};

    for (int half = 0; half < 2; ++half) {
        const int itile = half ? 31 - (int)blockIdx.x : (int)blockIdx.x;
        const int t0 = itile * 64;

        const bf8 aq = *(const bf8*)(Qg + (t0 + wv * 16 + l15) * HD + q * 8);
        f4 o0 = z4, o1 = z4;
        float m_st[4] = {-1e30f, -1e30f, -1e30f, -1e30f};
        float l_st[4] = {0.f, 0.f, 0.f, 0.f};

        for (int jt = 0; jt <= itile; ++jt) {
            const int s0 = jt * 64;
            const int ubase = TT - 64 - t0 + s0;
            __syncthreads();
            *(bf8*)(Ks  + krow * 40 + kc * 8) = *(const bf8*)(Kg + (s0 + krow) * HD + kc * 8);
            *(bf8*)(Vts + vrow * 72 + vc * 8) = *(const bf8*)(Vg + vrow * TT + s0 + vc * 8);
            #pragma unroll
            for (int kk = 0; kk < 2; ++kk) {
                const int i  = tid + kk * 256;
                const int pr = i >> 2, pc = i & 3;
                const int u  = ubase + pr;
                bf8 val = {0,0,0,0,0,0,0,0};
                if (u < TT) val = *(const bf8*)(Pg + (long)u * HD + pc * 8);
                *(bf8*)(PEs + pr * 40 + pc * 8) = val;
            }
            __syncthreads();

            f4 sa[4], ra[5];
            #pragma unroll
            for (int nt = 0; nt < 4; ++nt) {
                const bf8 bk = *(const bf8*)(Ks + (nt * 16 + l15) * 40 + q * 8);
                sa[nt] = __builtin_amdgcn_mfma_f32_16x16x32_bf16(aq, bk, z4, 0, 0, 0);
            }
            const int pebase = 48 - 16 * wv;
            #pragma unroll
            for (int nt = 0; nt < 5; ++nt) {
                const bf8 bp = *(const bf8*)(PEs + (pebase + nt * 16 + l15) * 40 + q * 8);
                ra[nt] = __builtin_amdgcn_mfma_f32_16x16x32_bf16(aq, bp, z4, 0, 0, 0);
            }

            // ---- skew gather: pack (ra[nb],ra[nb+1]) as bf16x2 -> ONE bpermute ----
            unsigned short rb[5][4];
            #pragma unroll
            for (int nt = 0; nt < 5; ++nt)
                #pragma unroll
                for (int r = 0; r < 4; ++r) rb[nt][r] = f2bf(ra[nt][r]);
            #pragma unroll
            for (int nb = 0; nb < 4; ++nb) {
                #pragma unroll
                for (int r = 0; r < 4; ++r) {
                    const unsigned packed = (unsigned)rb[nb][r] | ((unsigned)rb[nb + 1][r] << 16);
                    const int shift = 15 - 4 * q - r;          // 0..15
                    const int tcol  = l15 + shift;             // 0..30
                    const int src   = (q << 4) | (tcol & 15);
                    const unsigned v = (unsigned)__shfl((int)packed, src);
                    const unsigned sel = (tcol < 16) ? (v << 16) : (v & 0xFFFF0000u);
                    sa[nb][r] += __int_as_float((int)sel);
                }
            }

            if (jt == itile) {
                #pragma unroll
                for (int nb = 0; nb < 4; ++nb)
                    #pragma unroll
                    for (int r = 0; r < 4; ++r) {
                        const int s_l = nb * 16 + l15;
                        const int t_l = wv * 16 + 4 * q + r;
                        if (s_l > t_l) sa[nb][r] = -1e30f;
                    }
            }

            // ---- online softmax in log2 domain; reductions on VALU via DPP ----
            float corr[4];
            #pragma unroll
            for (int r = 0; r < 4; ++r) {
                float mx = fmaxf(fmaxf(sa[0][r], sa[1][r]), fmaxf(sa[2][r], sa[3][r]));
                mx = rowmax16(mx);
                const float mn = fmaxf(m_st[r], mx);
                corr[r] = exp2f(m_st[r] - mn);
                m_st[r] = mn;
                float rs = 0.f;
                #pragma unroll
                for (int nb = 0; nb < 4; ++nb) {
                    const float p = exp2f(sa[nb][r] - mn);
                    rs += p;
                    Psw[(4 * q + r) * 72 + nb * 16 + l15] = f2bf(p);
                }
                rs = rowsum16(rs);
                l_st[r] = l_st[r] * corr[r] + rs;
            }
            #pragma unroll
            for (int r = 0; r < 4; ++r) { o0[r] *= corr[r]; o1[r] *= corr[r]; }

            #pragma unroll
            for (int ks = 0; ks < 2; ++ks) {
                const bf8 ap  = *(const bf8*)(Psw + l15 * 72 + ks * 32 + q * 8);
                const bf8 bv0 = *(const bf8*)(Vts + l15 * 72 + ks * 32 + q * 8);
                const bf8 bv1 = *(const bf8*)(Vts + (16 + l15) * 72 + ks * 32 + q * 8);
                o0 = __builtin_amdgcn_mfma_f32_16x16x32_bf16(ap, bv0, o0, 0, 0, 0);
                o1 = __builtin_amdgcn_mfma_f32_16x16x32_bf16(ap, bv1, o1, 0, 0, 0);
            }
        }

        #pragma unroll
        for (int r = 0; r < 4; ++r) {
            const float inv = 1.0f / l_st[r];
            const int t = t0 + wv * 16 + 4 * q + r;
            unsigned short* dst = att + ((long)(b * TT + t)) * NEMB + h * HD;
            dst[l15]      = f2bf(o0[r] * inv);
            dst[16 + l15] = f2bf(o1[r] * inv);
        }
    }
}

// ---------------- Kernel C: MFMA proj GEMM + bias ----------------------------
__global__ __launch_bounds__(256) void proj_mfma(const unsigned short* __restrict__ Ag,
                                                 const unsigned short* __restrict__ Bg,
                                                 const float* __restrict__ bias,
                                                 float* __restrict__ out) {
    __shared__ unsigned short sm[13824];
    unsigned short* As = sm;                         // [128][72]
    unsigned short* Bs = sm + 9216;                  // [64][72]
    const int tid = threadIdx.x;
    const int wv = tid >> 6, L = tid & 63;
    const int l15 = L & 15, q = L >> 4;
    const int n0 = blockIdx.x * 64;
    const int m0 = blockIdx.y * 128;

    f4 acc[2][4];
    #pragma unroll
    for (int mt = 0; mt < 2; ++mt)
        #pragma unroll
        for (int nt = 0; nt < 4; ++nt) acc[mt][nt] = (f4){0.f,0.f,0.f,0.f};

    for (int kc = 0; kc < 4; ++kc) {
        const int k0 = kc * 64;
        __syncthreads();
        #pragma unroll
        for (int p = 0; p < 4; ++p) {
            const int i = tid + p * 256;
            const int r = i >> 3, c = i & 7;
            *(bf8*)(As + r * 72 + c * 8) = *(const bf8*)(Ag + (long)(m0 + r) * 256 + k0 + c * 8);
        }
        #pragma unroll
        for (int p = 0; p < 2; ++p) {
            const int i = tid + p * 256;
            const int r = i >> 3, c = i & 7;
            *(bf8*)(Bs + r * 72 + c * 8) = *(const bf8*)(Bg + (long)(n0 + r) * 256 + k0 + c * 8);
        }
        __syncthreads();
        #pragma unroll
        for (int kk = 0; kk < 2; ++kk) {
            const bf8 a0 = *(const bf8*)(As + (wv * 32 + l15) * 72 + kk * 32 + q * 8);
            const bf8 a1 = *(const bf8*)(As + (wv * 32 + 16 + l15) * 72 + kk * 32 + q * 8);
            #pragma unroll
            for (int nt = 0; nt < 4; ++nt) {
                const bf8 bb = *(const bf8*)(Bs + (nt * 16 + l15) * 72 + kk * 32 + q * 8);
                acc[0][nt] = __builtin_amdgcn_mfma_f32_16x16x32_bf16(a0, bb, acc[0][nt], 0, 0, 0);
                acc[1][nt] = __builtin_amdgcn_mfma_f32_16x16x32_bf16(a1, bb, acc[1][nt], 0, 0, 0);
            }
        }
    }

    #pragma unroll
    for (int mt = 0; mt < 2; ++mt) {
        const int gm = m0 + wv * 32 + mt * 16 + q * 4;
        #pragma unroll
        for (int nt = 0; nt < 4; ++nt) {
            const int gn = n0 + nt * 16 + l15;
            const float bv = bias[gn];
            #pragma unroll
            for (int r = 0; r < 4; ++r)
                out[(long)(gm + r) * NEMB + gn] = acc[mt][nt][r] + bv;
        }
    }
}

extern "C" void kernel_launch(void* const* d_in, const int* in_sizes, int n_in,
                              void* d_out, int out_size, void* d_ws, size_t ws_size,
                              hipStream_t stream) {
    const float* x      = (const float*)d_in[0];
    const float* w_attn = (const float*)d_in[1];
    const float* pe     = (const float*)d_in[2];
    const float* w_proj = (const float*)d_in[3];
    const float* b_proj = (const float*)d_in[4];
    float* out = (float*)d_out;

    char* base = (char*)d_ws;
    unsigned short* xb   = (unsigned short*)(base);                    // 4 MB
    unsigned short* Kb   = (unsigned short*)(base + ( 4u << 20));      // 4 MB
    unsigned short* Qb   = (unsigned short*)(base + ( 8u << 20));      // 4 MB
    unsigned short* Vt   = (unsigned short*)(base + (12u << 20));      // 4 MB
    unsigned short* attb = (unsigned short*)(base + (16u << 20));      // 4 MB
    unsigned short* peb  = (unsigned short*)(base + (20u << 20));      // 1 MB
    unsigned short* waT  = (unsigned short*)(base + (21u << 20));      // 384 KB
    unsigned short* wpT  = (unsigned short*)(base + (22u << 20));      // 128 KB

    prep<<<dim3(2624), 256, 0, stream>>>(x, xb, pe, peb, w_attn, waT, w_proj, wpT);
    qkv_mfma<<<dim3(12, 64), 256, 0, stream>>>(xb, waT, Kb, Qb, Vt);
    attn_kernel<<<dim3(16, NH, BB), 256, 0, stream>>>(Kb, Qb, Vt, peb, attb);
    proj_mfma<<<dim3(4, 64), 256, 0, stream>>>(attb, wpT, b_proj, out);
}